// Round 3
// baseline (200.261 us; speedup 1.0000x reference)
//
#include <hip/hip_runtime.h>
#include <hip/hip_bf16.h>
#include <stdint.h>

// ---- problem constants ----
#define C_CLS  100000
#define DDIM   512
#define BROWS  512
#define NT     64          // classes per block
#define NSTEP  16          // K steps of 32
#define EPSN   1e-5f

typedef __attribute__((ext_vector_type(8))) short short8;
typedef __attribute__((ext_vector_type(4))) float f32x4;

__device__ inline unsigned pk2(float a, float b) {
  __hip_bfloat162 h = __float22bfloat162_rn(make_float2(a, b));
  unsigned u; __builtin_memcpy(&u, &h, 4); return u;
}

// Normalize each input row -> bf16, store in MFMA A-fragment order:
// elem idx (16B cells) = (s*32 + r16)*64 + khalf*16 + row
//   where s = k>>5 (K-step), r16 = b>>4 (row tile), khalf = (k>>3)&3, row = b&15.
// Per (wave, step) the 4 m-frags are then contiguous within 4KB (imm offsets).
__global__ void __launch_bounds__(64) k_norm_input(const float* __restrict__ in,
                                                   uint4* __restrict__ xnf,
                                                   float* __restrict__ out) {
  int b = blockIdx.x;
  int lane = threadIdx.x;              // lane covers k = lane*8 .. +7
  if (b == 0 && lane == 0) out[0] = 0.f;   // fold k_zero: gemm/label accumulate into out
  const float4* row = (const float4*)(in + b * DDIM);
  float4 v0 = row[lane * 2];
  float4 v1 = row[lane * 2 + 1];
  float ss = v0.x*v0.x + v0.y*v0.y + v0.z*v0.z + v0.w*v0.w
           + v1.x*v1.x + v1.y*v1.y + v1.z*v1.z + v1.w*v1.w;
#pragma unroll
  for (int o = 32; o >= 1; o >>= 1) ss += __shfl_xor(ss, o, 64);
  float sc = 1.f / fmaxf(sqrtf(ss), EPSN);
  uint4 o4;
  o4.x = pk2(v0.x*sc, v0.y*sc);
  o4.y = pk2(v0.z*sc, v0.w*sc);
  o4.z = pk2(v1.x*sc, v1.y*sc);
  o4.w = pk2(v1.z*sc, v1.w*sc);
  int idx = ((lane >> 2) * 32 + (b >> 4)) * 64 + (lane & 3) * 16 + (b & 15);
  xnf[idx] = o4;
}

// Fused GEMM + loss. 512 threads (8 waves) = all 512 rows x 64 classes.
// A: L2->reg, double-buffered one step ahead. W: HBM->reg (2-step lead) ->
// bf16 -> fragment-layout LDS (XOR-swizzled cells), 4-buffer rotation, one
// raw end-of-step barrier (lgkmcnt only — W/A loads stay in flight across it).
__global__ void __launch_bounds__(512, 4) k_gemm(const uint4* __restrict__ xnf,
                                                 const float* __restrict__ wt,
                                                 const float* __restrict__ bias,
                                                 float* __restrict__ out) {
  __shared__ __align__(16) unsigned char sW[4][4096];
  __shared__ float sNsq[NT];
  __shared__ float sRed[8];

  const int tid  = threadIdx.x;
  const int lane = tid & 63;
  const int wv   = tid >> 6;
  const int cbase = blockIdx.x * NT;

  // W staging: thread t handles class cls = t>>3, k-quad q = t&7 (4 floats)
  const int cls = tid >> 3;
  const int q   = tid & 7;
  int wcls = cbase + cls;
  if (wcls >= C_CLS) wcls = C_CLS - 1;          // clamp; masked in epilogue
  const float4* wsrc = (const float4*)(wt + (size_t)wcls * DDIM) + q;
  // fragment cell = (cls>>4)*64 + (q>>1)*16 + (cls&15); byte XOR-swizzled by
  // cell[5:4] into bits [5:4] -> write conflicts 4-way -> 1-way, reads stay free.
  const int wcell = (cls >> 4) * 64 + (q >> 1) * 16 + (cls & 15);
  const int wbyte = ((wcell * 16) ^ (((wcell >> 4) & 3) << 4)) + (q & 1) * 8;
  const int rbyte = (lane * 16) ^ (((lane >> 4) & 3) << 4);   // + n*1024 imm

  const uint4* abase = xnf + wv * 256 + lane;   // + s*2048 + m*64

  float wsq = 0.f;
  f32x4 acc[4][4];
#pragma unroll
  for (int m = 0; m < 4; m++)
#pragma unroll
    for (int n = 0; n < 4; n++) acc[m][n] = (f32x4)(0.f);

  auto loadA = [&](short8* af, int s) {
#pragma unroll
    for (int m = 0; m < 4; m++)
      af[m] = *(const short8*)(abase + s * 2048 + m * 64);
  };
  auto cvt_write = [&](const float4& w, int bufi) {
    wsq += w.x*w.x + w.y*w.y + w.z*w.z + w.w*w.w;
    uint2 d;
    d.x = pk2(w.x, w.y);
    d.y = pk2(w.z, w.w);
    *(uint2*)(&sW[bufi][wbyte]) = d;
  };
  auto barrier = [&]() {
    __builtin_amdgcn_sched_barrier(0);
    asm volatile("s_waitcnt lgkmcnt(0)" ::: "memory");
    __builtin_amdgcn_s_barrier();
    __builtin_amdgcn_sched_barrier(0);
  };
  // step s: buf[s&3] ready. Issue A(s+1) loads; write W(s+1) (loaded 2 steps
  // ago -> no vmcnt stall); reload same reg with W(s+3); MFMA; barrier.
  auto step = [&](int s, float4& wreg, short8* afc, short8* afn) {
    if (s + 1 < NSTEP) loadA(afn, s + 1);
    if (s + 1 < NSTEP) cvt_write(wreg, (s + 1) & 3);
    if (s + 3 < NSTEP) wreg = wsrc[(s + 3) * 8];
    const unsigned char* Wb = sW[s & 3];
#pragma unroll
    for (int n = 0; n < 4; n++) {
      short8 wf = *(const short8*)(Wb + n * 1024 + rbyte);
#pragma unroll
      for (int m = 0; m < 4; m++)
        acc[m][n] = __builtin_amdgcn_mfma_f32_16x16x32_bf16(afc[m], wf, acc[m][n], 0, 0, 0);
    }
    if (s + 1 < NSTEP) barrier();
  };

  // prologue: buf0 <- W0 (one unavoidable HBM-latency stall); W1,W2 in regs
  short8 af0[4], af1[4];
  loadA(af0, 0);
  float4 w0 = wsrc[0];
  float4 wA = wsrc[8];     // W(1)
  float4 wB = wsrc[16];    // W(2)
  cvt_write(w0, 0);
  barrier();

#pragma unroll
  for (int s = 0; s < NSTEP; s++) {
    if (s & 1) step(s, wB, af1, af0);
    else       step(s, wA, af0, af1);
  }

  // ---- per-class norm^2 reduce (8 staging threads per class) ----
#pragma unroll
  for (int o = 1; o < 8; o <<= 1) wsq += __shfl_xor(wsq, o, 64);
  if ((tid & 7) == 0) sNsq[cls] = wsq;
  __syncthreads();

  // ---- epilogue: loss over 64 acc elements / thread ----
  const float bv = bias[0];
  float sum = 0.f;
#pragma unroll
  for (int n = 0; n < 4; n++) {
    int cl = n * 16 + (lane & 15);
    float rn = 1.f / fmaxf(sqrtf(sNsq[cl]), EPSN);
    bool valid = (cbase + cl) < C_CLS;
#pragma unroll
    for (int m = 0; m < 4; m++) {
#pragma unroll
      for (int i = 0; i < 4; i++) {
        float cosv = acc[m][n][i] * rn;
        float x = fminf(fmaf(cosv, 64.f, -bv), 64.f); // lower clip irrelevant (exp underflow)
        float z = __expf(x);
        float l = z * fmaf(z, fmaf(z, 0.33333333f, -0.5f), 1.f); // log1p, z small
        if (z > 0.03125f) l = __logf(1.f + z);        // rare branch (~1e-4 of lanes)
        sum += valid ? l : 0.f;
      }
    }
  }
#pragma unroll
  for (int o = 32; o >= 1; o >>= 1) sum += __shfl_xor(sum, o, 64);
  if (lane == 0) sRed[wv] = sum;
  __syncthreads();
  if (tid == 0) {
    float t = 0.f;
#pragma unroll
    for (int i = 0; i < 8; i++) t += sRed[i];
    atomicAdd(out, t * (1.f / 512.f));
  }
}

// Label correction: replace n_loss(b, label_b) by p_loss(b, label_b), full f32.
__global__ void __launch_bounds__(64) k_label(const float* __restrict__ in,
                                              const float* __restrict__ wt,
                                              const int* __restrict__ label,
                                              const float* __restrict__ bias,
                                              float* __restrict__ out) {
  int b = blockIdx.x;
  int lane = threadIdx.x;
  int c = label[b];
  const float4* xr = (const float4*)(in + b * DDIM);
  const float4* wr = (const float4*)(wt + (size_t)c * DDIM);
  float dt = 0.f, sx = 0.f, sw = 0.f;
#pragma unroll
  for (int i = 0; i < 2; i++) {
    float4 x = xr[lane * 2 + i];
    float4 w = wr[lane * 2 + i];
    dt += x.x*w.x + x.y*w.y + x.z*w.z + x.w*w.w;
    sx += x.x*x.x + x.y*x.y + x.z*x.z + x.w*x.w;
    sw += w.x*w.x + w.y*w.y + w.z*w.z + w.w*w.w;
  }
#pragma unroll
  for (int o = 32; o >= 1; o >>= 1) {
    dt += __shfl_xor(dt, o, 64);
    sx += __shfl_xor(sx, o, 64);
    sw += __shfl_xor(sw, o, 64);
  }
  if (lane == 0) {
    float bv = bias[0];
    float cosv = dt / (fmaxf(sqrtf(sx), EPSN) * fmaxf(sqrtf(sw), EPSN));
    float cp = 64.f * (cosv - 0.4f) - bv;
    cp = fminf(fmaxf(cp, -64.f), 64.f);
    float pl = log1pf(expf(-cp));
    float cn = 64.f * cosv - bv;
    cn = fminf(fmaxf(cn, -64.f), 64.f);
    float nl = log1pf(expf(cn));
    atomicAdd(out, (pl - nl) * (1.f / 512.f));
  }
}

extern "C" void kernel_launch(void* const* d_in, const int* in_sizes, int n_in,
                              void* d_out, int out_size, void* d_ws, size_t ws_size,
                              hipStream_t stream) {
  const float* input  = (const float*)d_in[0];
  const int*   label  = (const int*)d_in[1];
  const float* weight = (const float*)d_in[2];
  const float* bias   = (const float*)d_in[3];
  float* out = (float*)d_out;

  uint4* xnf = (uint4*)d_ws;   // 512 KB

  k_norm_input<<<BROWS, 64, 0, stream>>>(input, xnf, out);
  k_gemm<<<(C_CLS + NT - 1) / NT, 512, 0, stream>>>(xnf, weight, bias, out);
  k_label<<<BROWS, 64, 0, stream>>>(input, weight, label, bias, out);
}

// Round 4
// 108.906 us; speedup vs baseline: 1.8388x; 1.8388x over previous
//
#include <hip/hip_runtime.h>
#include <hip/hip_bf16.h>
#include <stdint.h>

// ---- problem constants ----
#define C_CLS  100000
#define DDIM   512
#define BROWS  512
#define NT     64          // classes per block
#define NSTEP  16          // K steps of 32
#define EPSN   1e-5f

typedef __attribute__((ext_vector_type(8))) short short8;
typedef __attribute__((ext_vector_type(4))) float f32x4;

__device__ inline unsigned pk2(float a, float b) {
  __hip_bfloat162 h = __float22bfloat162_rn(make_float2(a, b));
  unsigned u; __builtin_memcpy(&u, &h, 4); return u;
}

// Normalize each input row -> bf16, store in MFMA A-fragment order:
// cell idx (16B) = (s*32 + r16)*64 + khalf*16 + row, s=k>>5, r16=b>>4,
// khalf=(k>>3)&3, row=b&15. Each wave's (s, m) frag is a contiguous 1KB.
__global__ void __launch_bounds__(64) k_norm_input(const float* __restrict__ in,
                                                   uint4* __restrict__ xnf,
                                                   float* __restrict__ out) {
  int b = blockIdx.x;
  int lane = threadIdx.x;              // lane covers k = lane*8 .. +7
  if (b == 0 && lane == 0) out[0] = 0.f;   // gemm/label accumulate into out
  const float4* row = (const float4*)(in + b * DDIM);
  float4 v0 = row[lane * 2];
  float4 v1 = row[lane * 2 + 1];
  float ss = v0.x*v0.x + v0.y*v0.y + v0.z*v0.z + v0.w*v0.w
           + v1.x*v1.x + v1.y*v1.y + v1.z*v1.z + v1.w*v1.w;
#pragma unroll
  for (int o = 32; o >= 1; o >>= 1) ss += __shfl_xor(ss, o, 64);
  float sc = 1.f / fmaxf(sqrtf(ss), EPSN);
  uint4 o4;
  o4.x = pk2(v0.x*sc, v0.y*sc);
  o4.y = pk2(v0.z*sc, v0.w*sc);
  o4.z = pk2(v1.x*sc, v1.y*sc);
  o4.w = pk2(v1.z*sc, v1.w*sc);
  int idx = ((lane >> 2) * 32 + (b >> 4)) * 64 + (lane & 3) * 16 + (b & 15);
  xnf[idx] = o4;
}

// Fused GEMM + loss. 512 threads (8 waves) = all 512 rows x 64 classes.
// Phase 1: stage the block's ENTIRE W panel (64cls x 512k) f32->bf16 into
// 64KB frag-layout LDS (8 float4 in flight/thread), compute norms. ONE barrier.
// Phase 2: barrier-free — per wave 16 steps of {4 L2 A-frag loads,
// 4 conflict-free ds_reads, 16 MFMA}; TLP (16 waves/CU) hides latency.
__global__ void __launch_bounds__(512, 4) k_gemm(const uint4* __restrict__ xnf,
                                                 const float* __restrict__ wt,
                                                 const float* __restrict__ bias,
                                                 float* __restrict__ out) {
  __shared__ __align__(16) unsigned char sW[NSTEP][4096];
  __shared__ float sNsq[NT];
  __shared__ float sRed[8];

  const int tid  = threadIdx.x;
  const int lane = tid & 63;
  const int wv   = tid >> 6;
  const int cbase = blockIdx.x * NT;

  // W staging: thread t owns class cls = t>>3; quads q = (t&7) + 8j, j=0..15
  const int cls = tid >> 3;
  const int qb  = tid & 7;
  int wcls = cbase + cls;
  if (wcls >= C_CLS) wcls = C_CLS - 1;          // clamp; masked in epilogue
  const float4* wsrc = (const float4*)(wt + (size_t)wcls * DDIM) + qb;

  // frag cell for (cls, quad q): s=q>>3, n=cls>>4, khalf=(q>>1)&3, row=cls&15.
  // khalf is qb-only (8j adds multiples of 4); byte XOR-swizzle row^khalf (R2-proven).
  const int kh_ = (qb >> 1) & 3;
  const int wbyte = (cls >> 4) * 1024 + kh_ * 256
                  + (((cls & 15) * 16) ^ (kh_ << 4)) + (qb & 1) * 8;
  const int rbyte = (lane * 16) ^ (((lane >> 4) & 3) << 4);  // reader side, same XOR
  const uint4* abase = xnf + wv * 256 + lane;                 // + s*2048 + m*64

  // ---- phase 1: stream 128KB f32 panel, cvt, write LDS; per-class norm^2 ----
  float wsq = 0.f;
#pragma unroll
  for (int h = 0; h < 2; ++h) {
    float4 wr[8];
#pragma unroll
    for (int j = 0; j < 8; ++j) wr[j] = wsrc[(h * 8 + j) * 8];
#pragma unroll
    for (int j = 0; j < 8; ++j) {
      float4 w = wr[j];
      wsq += w.x*w.x + w.y*w.y + w.z*w.z + w.w*w.w;
      uint2 d;
      d.x = pk2(w.x, w.y);
      d.y = pk2(w.z, w.w);
      *(uint2*)(sW[h * 8 + j] + wbyte) = d;
    }
  }
#pragma unroll
  for (int o = 1; o < 8; o <<= 1) wsq += __shfl_xor(wsq, o, 64);
  if (qb == 0) sNsq[cls] = wsq;
  __syncthreads();   // the only block-wide barrier before epilogue

  // ---- phase 2: MFMA loop, no barriers ----
  f32x4 acc[4][4];
#pragma unroll
  for (int m = 0; m < 4; m++)
#pragma unroll
    for (int n = 0; n < 4; n++) acc[m][n] = (f32x4)(0.f);

#pragma unroll 1
  for (int s = 0; s < NSTEP; ++s) {
    short8 af[4];
#pragma unroll
    for (int m = 0; m < 4; m++)
      af[m] = *(const short8*)(abase + s * 2048 + m * 64);
    const unsigned char* Wb = sW[s];
#pragma unroll
    for (int n = 0; n < 4; n++) {
      short8 wf = *(const short8*)(Wb + n * 1024 + rbyte);
#pragma unroll
      for (int m = 0; m < 4; m++)
        acc[m][n] = __builtin_amdgcn_mfma_f32_16x16x32_bf16(af[m], wf, acc[m][n], 0, 0, 0);
    }
  }

  // ---- epilogue: loss over 64 acc elements / thread ----
  const float bv = bias[0];
  float sum = 0.f;
#pragma unroll
  for (int n = 0; n < 4; n++) {
    int cl = n * 16 + (lane & 15);
    float rn = 1.f / fmaxf(sqrtf(sNsq[cl]), EPSN);
    bool valid = (cbase + cl) < C_CLS;
#pragma unroll
    for (int m = 0; m < 4; m++) {
#pragma unroll
      for (int i = 0; i < 4; i++) {
        float cosv = acc[m][n][i] * rn;
        float x = fminf(fmaf(cosv, 64.f, -bv), 64.f); // lower clip irrelevant (exp underflow)
        float z = __expf(x);
        float l = z * fmaf(z, fmaf(z, 0.33333333f, -0.5f), 1.f); // log1p, z small
        if (z > 0.03125f) l = __logf(1.f + z);        // rare branch (~1e-4 of lanes)
        sum += valid ? l : 0.f;
      }
    }
  }
#pragma unroll
  for (int o = 32; o >= 1; o >>= 1) sum += __shfl_xor(sum, o, 64);
  if (lane == 0) sRed[wv] = sum;
  __syncthreads();
  if (tid == 0) {
    float t = 0.f;
#pragma unroll
    for (int i = 0; i < 8; i++) t += sRed[i];
    atomicAdd(out, t * (1.f / 512.f));
  }
}

// Label correction: replace n_loss(b, label_b) by p_loss(b, label_b), full f32.
__global__ void __launch_bounds__(64) k_label(const float* __restrict__ in,
                                              const float* __restrict__ wt,
                                              const int* __restrict__ label,
                                              const float* __restrict__ bias,
                                              float* __restrict__ out) {
  int b = blockIdx.x;
  int lane = threadIdx.x;
  int c = label[b];
  const float4* xr = (const float4*)(in + b * DDIM);
  const float4* wr = (const float4*)(wt + (size_t)c * DDIM);
  float dt = 0.f, sx = 0.f, sw = 0.f;
#pragma unroll
  for (int i = 0; i < 2; i++) {
    float4 x = xr[lane * 2 + i];
    float4 w = wr[lane * 2 + i];
    dt += x.x*w.x + x.y*w.y + x.z*w.z + x.w*w.w;
    sx += x.x*x.x + x.y*x.y + x.z*x.z + x.w*x.w;
    sw += w.x*w.x + w.y*w.y + w.z*w.z + w.w*w.w;
  }
#pragma unroll
  for (int o = 32; o >= 1; o >>= 1) {
    dt += __shfl_xor(dt, o, 64);
    sx += __shfl_xor(sx, o, 64);
    sw += __shfl_xor(sw, o, 64);
  }
  if (lane == 0) {
    float bv = bias[0];
    float cosv = dt / (fmaxf(sqrtf(sx), EPSN) * fmaxf(sqrtf(sw), EPSN));
    float cp = 64.f * (cosv - 0.4f) - bv;
    cp = fminf(fmaxf(cp, -64.f), 64.f);
    float pl = log1pf(expf(-cp));
    float cn = 64.f * cosv - bv;
    cn = fminf(fmaxf(cn, -64.f), 64.f);
    float nl = log1pf(expf(cn));
    atomicAdd(out, (pl - nl) * (1.f / 512.f));
  }
}

extern "C" void kernel_launch(void* const* d_in, const int* in_sizes, int n_in,
                              void* d_out, int out_size, void* d_ws, size_t ws_size,
                              hipStream_t stream) {
  const float* input  = (const float*)d_in[0];
  const int*   label  = (const int*)d_in[1];
  const float* weight = (const float*)d_in[2];
  const float* bias   = (const float*)d_in[3];
  float* out = (float*)d_out;

  uint4* xnf = (uint4*)d_ws;   // 512 KB

  k_norm_input<<<BROWS, 64, 0, stream>>>(input, xnf, out);
  k_gemm<<<(C_CLS + NT - 1) / NT, 512, 0, stream>>>(xnf, weight, bias, out);
  k_label<<<BROWS, 64, 0, stream>>>(input, weight, label, bias, out);
}

// Round 5
// 96.894 us; speedup vs baseline: 2.0668x; 1.1240x over previous
//
#include <hip/hip_runtime.h>
#include <hip/hip_bf16.h>
#include <stdint.h>

// ---- problem constants ----
#define C_CLS  100000
#define DDIM   512
#define BROWS  512
#define NT     64          // classes per block
#define NSTEP  16          // K steps of 32
#define EPSN   1e-5f

typedef __attribute__((ext_vector_type(8))) short short8;
typedef __attribute__((ext_vector_type(4))) float f32x4;

// d_ws float layout:
//   [0    .. 4096)  : 256 gemm accumulation slots, stride 16 floats (64B lines)
//   [4096 .. 5120)  : 64 label accumulation slots, stride 16 floats
//   byte 32768 ...  : xnf — bf16 A in MFMA fragment layout (512 KB)

__device__ inline unsigned pk2(float a, float b) {
  __hip_bfloat162 h = __float22bfloat162_rn(make_float2(a, b));
  unsigned u; __builtin_memcpy(&u, &h, 4); return u;
}

// Normalize each input row -> bf16, fragment order:
// cell idx (16B) = (s*32 + r16)*64 + khalf*16 + row; s=k>>5, r16=b>>4,
// khalf=(k>>3)&3, row=b&15. Also zeroes the ws accumulation slots.
__global__ void __launch_bounds__(64) k_norm_input(const float* __restrict__ in,
                                                   uint4* __restrict__ xnf,
                                                   float* __restrict__ ws) {
  int b = blockIdx.x;
  int lane = threadIdx.x;              // lane covers k = lane*8 .. +7
  if (lane == 0) {                     // zero accumulation slots
    if (b < 256) ws[b * 16] = 0.f;
    else if (b < 320) ws[4096 + (b - 256) * 16] = 0.f;
  }
  const float4* row = (const float4*)(in + b * DDIM);
  float4 v0 = row[lane * 2];
  float4 v1 = row[lane * 2 + 1];
  float ss = v0.x*v0.x + v0.y*v0.y + v0.z*v0.z + v0.w*v0.w
           + v1.x*v1.x + v1.y*v1.y + v1.z*v1.z + v1.w*v1.w;
#pragma unroll
  for (int o = 32; o >= 1; o >>= 1) ss += __shfl_xor(ss, o, 64);
  float sc = 1.f / fmaxf(sqrtf(ss), EPSN);
  uint4 o4;
  o4.x = pk2(v0.x*sc, v0.y*sc);
  o4.y = pk2(v0.z*sc, v0.w*sc);
  o4.z = pk2(v1.x*sc, v1.y*sc);
  o4.w = pk2(v1.z*sc, v1.w*sc);
  int idx = ((lane >> 2) * 32 + (b >> 4)) * 64 + (lane & 3) * 16 + (b & 15);
  xnf[idx] = o4;
}

// Fused GEMM + loss. 512 threads (8 waves) = all 512 rows x 64 classes.
// Phase 1: stage full 64-class W panel f32->bf16 into 64KB frag LDS
// (16 loads in flight), norms; ONE barrier. Phase 2: barrier-free, A-frag
// register double-buffer (next step's L2 loads overlap current MFMAs).
__global__ void __launch_bounds__(512, 4) k_gemm(const uint4* __restrict__ xnf,
                                                 const float* __restrict__ wt,
                                                 const float* __restrict__ bias,
                                                 float* __restrict__ ws) {
  __shared__ __align__(16) unsigned char sW[NSTEP][4096];
  __shared__ float sNsq[NT];
  __shared__ float sRed[8];

  const int tid  = threadIdx.x;
  const int lane = tid & 63;
  const int wv   = tid >> 6;
  const int cbase = blockIdx.x * NT;

  const int rbyte = (lane * 16) ^ (((lane >> 4) & 3) << 4);  // frag read, XOR-swz
  const uint4* abase = xnf + wv * 256 + lane;                 // + s*2048 + m*64

  short8 afA[4], afB[4];
  // A(0) loads FIRST — L2 latency hides under the W HBM stream.
#pragma unroll
  for (int m = 0; m < 4; m++)
    afA[m] = *(const short8*)(abase + m * 64);

  // ---- phase 1: W staging. thread t: class cls=t>>3, quads qb+8j ----
  const int cls = tid >> 3;
  const int qb  = tid & 7;
  int wcls = cbase + cls;
  if (wcls >= C_CLS) wcls = C_CLS - 1;          // clamp; masked in epilogue
  const float4* wsrc = (const float4*)(wt + (size_t)wcls * DDIM) + qb;
  const int kh_ = (qb >> 1) & 3;
  const int wbyte = (cls >> 4) * 1024 + kh_ * 256
                  + (((cls & 15) * 16) ^ (kh_ << 4)) + (qb & 1) * 8;

  float wsq = 0.f;
  {
    float4 wr0[8], wr1[8];
#pragma unroll
    for (int j = 0; j < 8; ++j) wr0[j] = wsrc[j * 8];
#pragma unroll
    for (int j = 0; j < 8; ++j) wr1[j] = wsrc[(8 + j) * 8];
#pragma unroll
    for (int j = 0; j < 8; ++j) {
      float4 w = wr0[j];
      wsq += w.x*w.x + w.y*w.y + w.z*w.z + w.w*w.w;
      uint2 d; d.x = pk2(w.x, w.y); d.y = pk2(w.z, w.w);
      *(uint2*)(sW[j] + wbyte) = d;
    }
#pragma unroll
    for (int j = 0; j < 8; ++j) {
      float4 w = wr1[j];
      wsq += w.x*w.x + w.y*w.y + w.z*w.z + w.w*w.w;
      uint2 d; d.x = pk2(w.x, w.y); d.y = pk2(w.z, w.w);
      *(uint2*)(sW[8 + j] + wbyte) = d;
    }
  }
#pragma unroll
  for (int o = 1; o < 8; o <<= 1) wsq += __shfl_xor(wsq, o, 64);
  if (qb == 0) sNsq[cls] = wsq;
  __syncthreads();   // the only block-wide barrier before epilogue

  // ---- phase 2: software-pipelined MFMA loop, no barriers ----
  f32x4 acc[4][4];
#pragma unroll
  for (int m = 0; m < 4; m++)
#pragma unroll
    for (int n = 0; n < 4; n++) acc[m][n] = (f32x4)(0.f);

  auto loadA = [&](short8* af, int s) {
#pragma unroll
    for (int m = 0; m < 4; m++)
      af[m] = *(const short8*)(abase + s * 2048 + m * 64);
  };
  auto compute = [&](int s, const short8* af) {
    const unsigned char* Wb = sW[s];
#pragma unroll
    for (int n = 0; n < 4; n++) {
      short8 wf = *(const short8*)(Wb + n * 1024 + rbyte);
#pragma unroll
      for (int m = 0; m < 4; m++)
        acc[m][n] = __builtin_amdgcn_mfma_f32_16x16x32_bf16(af[m], wf, acc[m][n], 0, 0, 0);
    }
  };

#pragma unroll 1
  for (int s2 = 0; s2 < NSTEP / 2; ++s2) {
    int s0 = s2 * 2;
    loadA(afB, s0 + 1);        // overlap with compute(s0)
    compute(s0, afA);
    if (s2 < NSTEP / 2 - 1) loadA(afA, s0 + 2);
    compute(s0 + 1, afB);
  }

  // ---- epilogue: loss over 64 acc elements / thread (~6 VALU/elem) ----
  const float bv = bias[0];
  float sum = 0.f;
#pragma unroll
  for (int n = 0; n < 4; n++) {
    int cl = n * 16 + (lane & 15);
    float s64 = 64.f / fmaxf(sqrtf(sNsq[cl]), EPSN);   // fold S and 1/||w||
    bool valid = (cbase + cl) < C_CLS;
#pragma unroll
    for (int m = 0; m < 4; m++) {
#pragma unroll
      for (int i = 0; i < 4; i++) {
        // x = 64*cos - bias <= ~51 < 64, so no upper clamp needed; lower
        // clip irrelevant (exp underflow). log1p(z) ~= z - z^2/2 for z<=1/32.
        float x = fmaf(acc[m][n][i], s64, -bv);
        float z = __expf(x);
        float l = fmaf(-0.5f * z, z, z);
        if (z > 0.03125f) l = __logf(1.f + z);  // rare (~1e-4 of elements)
        sum += valid ? l : 0.f;
      }
    }
  }
#pragma unroll
  for (int o = 32; o >= 1; o >>= 1) sum += __shfl_xor(sum, o, 64);
  if (lane == 0) sRed[wv] = sum;
  __syncthreads();
  if (tid == 0) {
    float t = 0.f;
#pragma unroll
    for (int i = 0; i < 8; i++) t += sRed[i];
    atomicAdd(&ws[(blockIdx.x & 255) * 16], t);   // spread across 256 lines
  }
}

// Label correction: replace n_loss(b, label_b) by p_loss(b, label_b), full f32.
__global__ void __launch_bounds__(64) k_label(const float* __restrict__ in,
                                              const float* __restrict__ wt,
                                              const int* __restrict__ label,
                                              const float* __restrict__ bias,
                                              float* __restrict__ ws) {
  int b = blockIdx.x;
  int lane = threadIdx.x;
  int c = label[b];
  const float4* xr = (const float4*)(in + b * DDIM);
  const float4* wr = (const float4*)(wt + (size_t)c * DDIM);
  float dt = 0.f, sx = 0.f, sw = 0.f;
#pragma unroll
  for (int i = 0; i < 2; i++) {
    float4 x = xr[lane * 2 + i];
    float4 w = wr[lane * 2 + i];
    dt += x.x*w.x + x.y*w.y + x.z*w.z + x.w*w.w;
    sx += x.x*x.x + x.y*x.y + x.z*x.z + x.w*x.w;
    sw += w.x*w.x + w.y*w.y + w.z*w.z + w.w*w.w;
  }
#pragma unroll
  for (int o = 32; o >= 1; o >>= 1) {
    dt += __shfl_xor(dt, o, 64);
    sx += __shfl_xor(sx, o, 64);
    sw += __shfl_xor(sw, o, 64);
  }
  if (lane == 0) {
    float bv = bias[0];
    float cosv = dt / (fmaxf(sqrtf(sx), EPSN) * fmaxf(sqrtf(sw), EPSN));
    float cp = 64.f * (cosv - 0.4f) - bv;
    cp = fminf(fmaxf(cp, -64.f), 64.f);
    float pl = log1pf(expf(-cp));
    float cn = 64.f * cosv - bv;
    cn = fminf(fmaxf(cn, -64.f), 64.f);
    float nl = log1pf(expf(cn));
    atomicAdd(&ws[4096 + (b & 63) * 16], pl - nl);
  }
}

// Merge the 256 gemm slots + 64 label slots, scale by 1/B.
__global__ void __launch_bounds__(64) k_final(const float* __restrict__ ws,
                                              float* __restrict__ out) {
  int lane = threadIdx.x;
  float s = ws[lane * 16] + ws[(lane + 64) * 16]
          + ws[(lane + 128) * 16] + ws[(lane + 192) * 16]
          + ws[4096 + lane * 16];
#pragma unroll
  for (int o = 32; o >= 1; o >>= 1) s += __shfl_xor(s, o, 64);
  if (lane == 0) out[0] = s * (1.f / 512.f);
}

extern "C" void kernel_launch(void* const* d_in, const int* in_sizes, int n_in,
                              void* d_out, int out_size, void* d_ws, size_t ws_size,
                              hipStream_t stream) {
  const float* input  = (const float*)d_in[0];
  const int*   label  = (const int*)d_in[1];
  const float* weight = (const float*)d_in[2];
  const float* bias   = (const float*)d_in[3];
  float* out = (float*)d_out;
  float* ws  = (float*)d_ws;
  uint4* xnf = (uint4*)((char*)d_ws + 32768);

  k_norm_input<<<BROWS, 64, 0, stream>>>(input, xnf, ws);
  k_gemm<<<(C_CLS + NT - 1) / NT, 512, 0, stream>>>(xnf, weight, bias, ws);
  k_label<<<BROWS, 64, 0, stream>>>(input, weight, label, bias, ws);
  k_final<<<1, 64, 0, stream>>>(ws, out);
}